// Round 3
// 312.031 us; speedup vs baseline: 1.0247x; 1.0247x over previous
//
#include <hip/hip_runtime.h>
#include <hip/hip_fp16.h>

// ---------------------------------------------------------------------------
// GCN 2-layer forward:  out = log_softmax( A_hat * relu(A_hat * (x W1) + b1) W2 + b2 )
// A_hat = D^-1/2 (A + I) D^-1/2, deg on dst. Edge index arrives as int32.
//
// R10: pull kernels restructured from latency-bound (1 node/wave, half2/lane,
// 4 loads in flight) to 4 edge-slots x 16 lanes/wave with half8 (L1) / half4
// (L2) loads -> 8 independent row-gathers in flight per wave; cross-slot
// shfl_xor(16/32) reduction; 32-bit byte-offset addressing off uniform base.
// CSR build + MFMA GEMMs unchanged from r9.
// ---------------------------------------------------------------------------

#define BSHIFT 9
#define BSIZE  512            // nodes per bucket; NB = ceil(N/512) = 196 < 256
#define P2_T   1024
#define P2_I   16             // edges staged per thread in partition pass

using half8 = __attribute__((ext_vector_type(8))) _Float16;
using half4 = __attribute__((ext_vector_type(4))) _Float16;
using f32x4 = __attribute__((ext_vector_type(4))) float;

// --- pass 1: per-bucket edge counts (coalesced dst read, LDS histogram) ----
__global__ __launch_bounds__(256) void bucket_hist_kernel(const int* __restrict__ dst, int E,
                                                          unsigned int* __restrict__ bcount, int NB) {
    __shared__ unsigned int h[256];
    int t = threadIdx.x;
    h[t] = 0u;
    __syncthreads();
    for (int i = blockIdx.x * 256 + t; i < E; i += gridDim.x * 256)
        atomicAdd(&h[dst[i] >> BSHIFT], 1u);
    __syncthreads();
    if (t < NB && h[t]) atomicAdd(&bcount[t], h[t]);
}

// --- scan bucket counts -> bucket_base bb[0..NB], bucket_fill bf -----------
__global__ __launch_bounds__(256) void bucket_scan_kernel(const unsigned int* __restrict__ bcount,
                                                          unsigned int* __restrict__ bb,
                                                          unsigned int* __restrict__ bf,
                                                          int NB, int E) {
    __shared__ unsigned int s[256];
    int t = threadIdx.x;
    unsigned int v = (t < NB) ? bcount[t] : 0u;
    s[t] = v;
    __syncthreads();
    for (int off = 1; off < 256; off <<= 1) {
        unsigned int u = s[t];
        if (t >= off) u += s[t - off];
        __syncthreads();
        s[t] = u;
        __syncthreads();
    }
    if (t < NB) {
        unsigned int ex = s[t] - v;
        bb[t] = ex;
        bf[t] = ex;
    }
    if (t == 0) bb[NB] = (unsigned int)E;
}

// --- pass 2: partition edges into dst-buckets, packed src|dstLocal<<17 -----
__global__ __launch_bounds__(1024) void partition_kernel(const int* __restrict__ src,
                                                         const int* __restrict__ dst,
                                                         unsigned int* __restrict__ bucket_fill,
                                                         unsigned int* __restrict__ ebuf,
                                                         int E, int NB) {
    __shared__ unsigned int hist[256];
    __shared__ unsigned int cur[256];
    int t = threadIdx.x;
    if (t < 256) hist[t] = 0u;
    __syncthreads();
    size_t base = (size_t)blockIdx.x * (P2_T * P2_I);
    int sv[P2_I], dv[P2_I];
#pragma unroll
    for (int i = 0; i < P2_I; ++i) {
        size_t idx = base + (size_t)i * P2_T + t;
        if (idx < (size_t)E) {
            sv[i] = src[idx];
            dv[i] = dst[idx];
            atomicAdd(&hist[dv[i] >> BSHIFT], 1u);
        } else dv[i] = -1;
    }
    __syncthreads();
    if (t < NB && hist[t] > 0u) cur[t] = atomicAdd(&bucket_fill[t], hist[t]);
    __syncthreads();
#pragma unroll
    for (int i = 0; i < P2_I; ++i) {
        if (dv[i] >= 0) {
            int b = dv[i] >> BSHIFT;
            unsigned int pos = atomicAdd(&cur[b], 1u);
            ebuf[pos] = (unsigned int)sv[i] | ((unsigned int)(dv[i] & (BSIZE - 1)) << 17);
        }
    }
}

// --- pass 3: per-bucket deg/dinv/rowptr in LDS + scatter; cursor=rowend ----
__global__ __launch_bounds__(256) void bucket_scatter2_kernel(const unsigned int* __restrict__ ebuf,
                                                              const unsigned int* __restrict__ bb,
                                                              unsigned int* __restrict__ cursor,
                                                              unsigned int* __restrict__ deg,
                                                              float* __restrict__ dinv,
                                                              int* __restrict__ col, int N) {
    __shared__ unsigned int ldeg[BSIZE];
    __shared__ unsigned int lcur[BSIZE];
    __shared__ unsigned int part[256];
    int b = blockIdx.x, t = threadIdx.x;
    int node0 = b << BSHIFT;
    int nn = min(BSIZE, N - node0);
    ldeg[t] = 0u;
    ldeg[t + 256] = 0u;
    __syncthreads();
    unsigned int e0 = bb[b], e1 = bb[b + 1];
    for (unsigned int e = e0 + t; e < e1; e += 256)
        atomicAdd(&ldeg[ebuf[e] >> 17], 1u);
    __syncthreads();
    unsigned int a0 = ldeg[2 * t], a1 = ldeg[2 * t + 1];
    part[t] = a0 + a1;
    __syncthreads();
    for (int off = 1; off < 256; off <<= 1) {
        unsigned int u = part[t];
        if (t >= off) u += part[t - off];
        __syncthreads();
        part[t] = u;
        __syncthreads();
    }
    unsigned int ex = part[t] - (a0 + a1);
    lcur[2 * t]     = e0 + ex;
    lcur[2 * t + 1] = e0 + ex + a0;
    __syncthreads();
    for (unsigned int e = e0 + t; e < e1; e += 256) {
        unsigned int p = ebuf[e];
        unsigned int pos = atomicAdd(&lcur[p >> 17], 1u);
        col[pos] = (int)(p & 0x1FFFFu);
    }
    __syncthreads();
    for (int i = t; i < nn; i += 256) {
        unsigned int d = ldeg[i];
        deg[node0 + i] = d;
        dinv[node0 + i] = rsqrtf((float)(d + 1u));
        cursor[node0 + i] = lcur[i];
    }
}

// --- swizzle W1 (128x128) and W2 (128x64) into MFMA B-fragment order -------
// w1s[((c*4+s)*64+l)*8+j] = W[k][n], k=(l>>4)*8+j+32s, n=16c+(l&15)
__global__ __launch_bounds__(256) void swizzle_w_kernel(const float* __restrict__ W1,
                                                        const float* __restrict__ W2,
                                                        __half* __restrict__ w1s,
                                                        __half* __restrict__ w2s) {
    int t = threadIdx.x;
    for (int i = t; i < 8 * 4 * 64 * 8; i += 256) {   // W1: 8 col-tiles
        int j = i & 7, l = (i >> 3) & 63, s = (i >> 9) & 3, c = i >> 11;
        int k = ((l >> 4) * 8) + j + 32 * s;
        int nn = 16 * c + (l & 15);
        w1s[i] = __float2half(W1[k * 128 + nn]);
    }
    for (int i = t; i < 4 * 4 * 64 * 8; i += 256) {   // W2: 4 col-tiles
        int j = i & 7, l = (i >> 3) & 63, s = (i >> 9) & 3, c = i >> 11;
        int k = ((l >> 4) * 8) + j + 32 * s;
        int nn = 16 * c + (l & 15);
        w2s[i] = __float2half(W2[k * 64 + nn]);
    }
}

// --- GEMM1 (MFMA): Y[r,128] = f16( dinv[r] * (X[r,128] @ W1) ), X fp32 -----
__global__ __launch_bounds__(256) void gemm1_mfma_kernel(const float* __restrict__ X,
                                                         const __half* __restrict__ w1s,
                                                         const float* __restrict__ dinv,
                                                         __half* __restrict__ Y, int n) {
    int t = threadIdx.x;
    int wave = t >> 6, lane = t & 63;
    int quad = lane >> 4, m = lane & 15;
    int rowbase = blockIdx.x * 64 + wave * 16;
    int arow = rowbase + m;
    bool aok = arow < n;
    const float* xr = X + (size_t)arow * 128 + quad * 8;

    half8 afrag[4];
#pragma unroll
    for (int s = 0; s < 4; ++s) {
        float4 p0 = make_float4(0.f, 0.f, 0.f, 0.f), p1 = p0;
        if (aok) {
            p0 = *(const float4*)(xr + s * 32);
            p1 = *(const float4*)(xr + s * 32 + 4);
        }
        afrag[s][0] = (_Float16)p0.x; afrag[s][1] = (_Float16)p0.y;
        afrag[s][2] = (_Float16)p0.z; afrag[s][3] = (_Float16)p0.w;
        afrag[s][4] = (_Float16)p1.x; afrag[s][5] = (_Float16)p1.y;
        afrag[s][6] = (_Float16)p1.z; afrag[s][7] = (_Float16)p1.w;
    }

    const half8* bp = (const half8*)w1s;
    f32x4 acc[8];
#pragma unroll
    for (int c = 0; c < 8; ++c) acc[c] = (f32x4){0.f, 0.f, 0.f, 0.f};
#pragma unroll
    for (int c = 0; c < 8; ++c)
#pragma unroll
        for (int s = 0; s < 4; ++s)
            acc[c] = __builtin_amdgcn_mfma_f32_16x16x32_f16(afrag[s], bp[(c * 4 + s) * 64 + lane], acc[c], 0, 0, 0);

#pragma unroll
    for (int i = 0; i < 4; ++i) {
        int row = rowbase + quad * 4 + i;
        if (row < n) {
            float w = dinv[row];
            __half* yr = Y + (size_t)row * 128 + m;
#pragma unroll
            for (int c = 0; c < 8; ++c) yr[c * 16] = __float2half(acc[c][i] * w);
        }
    }
}

// --- GEMM2 (MFMA): Y[r,64] = f16( dinv[r] * (Xh[r,128] @ W2) ), X fp16 -----
__global__ __launch_bounds__(256) void gemm2_mfma_kernel(const __half* __restrict__ X,
                                                         const __half* __restrict__ w2s,
                                                         const float* __restrict__ dinv,
                                                         __half* __restrict__ Y, int n) {
    int t = threadIdx.x;
    int wave = t >> 6, lane = t & 63;
    int quad = lane >> 4, m = lane & 15;
    int rowbase = blockIdx.x * 64 + wave * 16;
    int arow = rowbase + m;
    bool aok = arow < n;
    const __half* xr = X + (size_t)arow * 128 + quad * 8;

    half8 afrag[4];
#pragma unroll
    for (int s = 0; s < 4; ++s) {
        if (aok) afrag[s] = *(const half8*)(xr + s * 32);
        else     afrag[s] = (half8){0, 0, 0, 0, 0, 0, 0, 0};
    }

    const half8* bp = (const half8*)w2s;
    f32x4 acc[4];
#pragma unroll
    for (int c = 0; c < 4; ++c) acc[c] = (f32x4){0.f, 0.f, 0.f, 0.f};
#pragma unroll
    for (int c = 0; c < 4; ++c)
#pragma unroll
        for (int s = 0; s < 4; ++s)
            acc[c] = __builtin_amdgcn_mfma_f32_16x16x32_f16(afrag[s], bp[(c * 4 + s) * 64 + lane], acc[c], 0, 0, 0);

#pragma unroll
    for (int i = 0; i < 4; ++i) {
        int row = rowbase + quad * 4 + i;
        if (row < n) {
            float w = dinv[row];
            __half* yr = Y + (size_t)row * 64 + m;
#pragma unroll
            for (int c = 0; c < 4; ++c) yr[c * 16] = __float2half(acc[c][i] * w);
        }
    }
}

// --- pull layer 1: H[d] = relu(dinv[d]*(T'[d] + sum T'[col]) + b1), F=128 --
// R10: 1 node/wave, 4 edge-slots x 16 lanes, half8 (16B) per lane.
// 8 independent 256B row-gathers in flight per wave (slot-parallel, unroll 2).
__global__ __launch_bounds__(256) void pull_agg1_kernel(const __half* __restrict__ T,
                                                        const int* __restrict__ col,
                                                        const unsigned int* __restrict__ cursor,
                                                        const unsigned int* __restrict__ deg,
                                                        const float* __restrict__ dinv,
                                                        const float* __restrict__ b1,
                                                        __half* __restrict__ H, int N) {
    int node = blockIdx.x * 4 + (threadIdx.x >> 6);
    if (node >= N) return;
    int lane = threadIdx.x & 63;
    int q = lane >> 4, sl = lane & 15;          // edge slot / sub-lane
    unsigned int end = cursor[node];
    unsigned int e = (end - deg[node]) + (unsigned int)q;
    const char* Tb = (const char*)T;            // row stride 256 B
    unsigned int coff = (unsigned int)sl << 4;  // 16 B per sub-lane

    float acc[8];
#pragma unroll
    for (int j = 0; j < 8; ++j) acc[j] = 0.f;
    if (q == 0) {                               // self loop on slot 0
        half8 v = *(const half8*)(Tb + (((unsigned int)node) << 8) + coff);
#pragma unroll
        for (int j = 0; j < 8; ++j) acc[j] = (float)v[j];
    }

    for (; e + 4 < end; e += 8) {               // 2 edges/slot in flight
        unsigned int s0 = (unsigned int)col[e];
        unsigned int s1 = (unsigned int)col[e + 4];
        half8 v0 = *(const half8*)(Tb + (s0 << 8) + coff);
        half8 v1 = *(const half8*)(Tb + (s1 << 8) + coff);
#pragma unroll
        for (int j = 0; j < 8; ++j) acc[j] += (float)v0[j] + (float)v1[j];
    }
    if (e < end) {
        unsigned int s0 = (unsigned int)col[e];
        half8 v0 = *(const half8*)(Tb + (s0 << 8) + coff);
#pragma unroll
        for (int j = 0; j < 8; ++j) acc[j] += (float)v0[j];
    }

#pragma unroll
    for (int j = 0; j < 8; ++j) {               // cross-slot reduce
        acc[j] += __shfl_xor(acc[j], 16);
        acc[j] += __shfl_xor(acc[j], 32);
    }

    if (q == 0) {
        float w = dinv[node];
        const float4* bp = (const float4*)b1;
        float4 ba = bp[sl * 2], bbv = bp[sl * 2 + 1];
        half8 o;
        o[0] = (_Float16)fmaxf(fmaf(w, acc[0], ba.x), 0.f);
        o[1] = (_Float16)fmaxf(fmaf(w, acc[1], ba.y), 0.f);
        o[2] = (_Float16)fmaxf(fmaf(w, acc[2], ba.z), 0.f);
        o[3] = (_Float16)fmaxf(fmaf(w, acc[3], ba.w), 0.f);
        o[4] = (_Float16)fmaxf(fmaf(w, acc[4], bbv.x), 0.f);
        o[5] = (_Float16)fmaxf(fmaf(w, acc[5], bbv.y), 0.f);
        o[6] = (_Float16)fmaxf(fmaf(w, acc[6], bbv.z), 0.f);
        o[7] = (_Float16)fmaxf(fmaf(w, acc[7], bbv.w), 0.f);
        *(half8*)((char*)H + (((unsigned int)node) << 8) + coff) = o;
    }
}

// --- pull layer 2 + logsoftmax: out[d] = lsm(dinv[d]*sum + b2), F=64 -------
// R10: same 4-slot structure, half4 (8B) per lane, row stride 128 B.
__global__ __launch_bounds__(256) void pull_agg2_kernel(const __half* __restrict__ T,
                                                        const int* __restrict__ col,
                                                        const unsigned int* __restrict__ cursor,
                                                        const unsigned int* __restrict__ deg,
                                                        const float* __restrict__ dinv,
                                                        const float* __restrict__ b2,
                                                        float* __restrict__ OUT, int N) {
    int node = blockIdx.x * 4 + (threadIdx.x >> 6);
    if (node >= N) return;
    int lane = threadIdx.x & 63;
    int q = lane >> 4, sl = lane & 15;
    unsigned int end = cursor[node];
    unsigned int e = (end - deg[node]) + (unsigned int)q;
    const char* Tb = (const char*)T;            // row stride 128 B
    unsigned int coff = (unsigned int)sl << 3;  // 8 B per sub-lane

    float acc[4];
#pragma unroll
    for (int j = 0; j < 4; ++j) acc[j] = 0.f;
    if (q == 0) {                               // self loop on slot 0
        half4 v = *(const half4*)(Tb + (((unsigned int)node) << 7) + coff);
#pragma unroll
        for (int j = 0; j < 4; ++j) acc[j] = (float)v[j];
    }

    for (; e + 4 < end; e += 8) {
        unsigned int s0 = (unsigned int)col[e];
        unsigned int s1 = (unsigned int)col[e + 4];
        half4 v0 = *(const half4*)(Tb + (s0 << 7) + coff);
        half4 v1 = *(const half4*)(Tb + (s1 << 7) + coff);
#pragma unroll
        for (int j = 0; j < 4; ++j) acc[j] += (float)v0[j] + (float)v1[j];
    }
    if (e < end) {
        unsigned int s0 = (unsigned int)col[e];
        half4 v0 = *(const half4*)(Tb + (s0 << 7) + coff);
#pragma unroll
        for (int j = 0; j < 4; ++j) acc[j] += (float)v0[j];
    }

#pragma unroll
    for (int j = 0; j < 4; ++j) {               // cross-slot reduce
        acc[j] += __shfl_xor(acc[j], 16);
        acc[j] += __shfl_xor(acc[j], 32);
    }

    float w = dinv[node];
    float4 b = ((const float4*)b2)[sl];
    float v0 = fmaf(w, acc[0], b.x);
    float v1 = fmaf(w, acc[1], b.y);
    float v2 = fmaf(w, acc[2], b.z);
    float v3 = fmaf(w, acc[3], b.w);
    float m = fmaxf(fmaxf(v0, v1), fmaxf(v2, v3));
#pragma unroll
    for (int off = 8; off > 0; off >>= 1) m = fmaxf(m, __shfl_xor(m, off));
    float sum = __expf(v0 - m) + __expf(v1 - m) + __expf(v2 - m) + __expf(v3 - m);
#pragma unroll
    for (int off = 8; off > 0; off >>= 1) sum += __shfl_xor(sum, off);
    float ls = m + logf(sum);
    if (q == 0) {
        float4 o = make_float4(v0 - ls, v1 - ls, v2 - ls, v3 - ls);
        *(float4*)(OUT + (size_t)node * 64 + sl * 4) = o;
    }
}

extern "C" void kernel_launch(void* const* d_in, const int* in_sizes, int n_in,
                              void* d_out, int out_size, void* d_ws, size_t ws_size,
                              hipStream_t stream) {
    const float* x   = (const float*)d_in[0];
    const int*   ei  = (const int*)d_in[1];   // int32 per harness contract
    const float* W1  = (const float*)d_in[2];
    const float* b1  = (const float*)d_in[3];
    const float* W2  = (const float*)d_in[4];
    const float* b2  = (const float*)d_in[5];
    float*       out = (float*)d_out;

    const int N = in_sizes[0] / 128;      // 100000
    const int E = in_sizes[1] / 2;        // 1600000
    const int* src = ei;
    const int* dst = ei + E;
    const int NB = (N + BSIZE - 1) >> BSHIFT;   // dst buckets (196 <= 256)

    // workspace layout
    char* ws = (char*)d_ws;
    size_t off = 0;
    auto alloc = [&](size_t bytes) { void* p = ws + off; off = (off + bytes + 255) & ~(size_t)255; return p; };
    unsigned int* deg    = (unsigned int*)alloc((size_t)N * 4);
    float*        dinv   = (float*)alloc((size_t)N * 4);
    unsigned int* cursor = (unsigned int*)alloc((size_t)N * 4);
    unsigned int* bcount = (unsigned int*)alloc(256 * 4);
    unsigned int* bb     = (unsigned int*)alloc(257 * 4);       // bucket_base
    unsigned int* bf     = (unsigned int*)alloc(256 * 4);       // bucket_fill
    __half*       w1s    = (__half*)alloc(128 * 128 * 2);       // swizzled W1
    __half*       w2s    = (__half*)alloc(128 * 64 * 2);        // swizzled W2
    int*          col    = (int*)alloc((size_t)E * 4);
    __half*       A      = (__half*)alloc((size_t)N * 128 * 2); // T1'/T2' fp16
    __half*       B      = (__half*)alloc((size_t)N * 128 * 2); // h fp16
    unsigned int* ebuf   = (unsigned int*)alloc((size_t)E * 4);

    // 1. CSR build: bucket hist -> scan -> partition -> per-bucket scatter
    hipMemsetAsync(bcount, 0, 256 * 4, stream);
    bucket_hist_kernel<<<(E + 4095) / 4096, 256, 0, stream>>>(dst, E, bcount, NB);
    bucket_scan_kernel<<<1, 256, 0, stream>>>(bcount, bb, bf, NB, E);
    partition_kernel<<<(E + P2_T * P2_I - 1) / (P2_T * P2_I), P2_T, 0, stream>>>(src, dst, bf, ebuf, E, NB);
    bucket_scatter2_kernel<<<NB, 256, 0, stream>>>(ebuf, bb, cursor, deg, dinv, col, N);
    // now cursor[i] == rowend(i); rowstart(i) = cursor[i] - deg[i]; dinv ready

    // 1b. swizzle weights into MFMA fragment order (runs alongside CSR chain)
    swizzle_w_kernel<<<1, 256, 0, stream>>>(W1, W2, w1s, w2s);

    // 2. T1' = dinv * (x @ W1) [MFMA, fp16 out];  h = relu(dinv*(pull) + b1)
    gemm1_mfma_kernel<<<(N + 63) / 64, 256, 0, stream>>>(x, w1s, dinv, A, N);
    pull_agg1_kernel<<<(N + 3) / 4, 256, 0, stream>>>(A, col, cursor, deg, dinv, b1, B, N);

    // 3. T2' = dinv * (h @ W2) [MFMA];  out = logsoftmax(dinv*(pull) + b2)
    gemm2_mfma_kernel<<<(N + 63) / 64, 256, 0, stream>>>(B, w2s, dinv, A, N);
    pull_agg2_kernel<<<(N + 3) / 4, 256, 0, stream>>>(A, col, cursor, deg, dinv, b2, out, N);
}

// Round 4
// 310.486 us; speedup vs baseline: 1.0298x; 1.0050x over previous
//
#include <hip/hip_runtime.h>
#include <hip/hip_fp16.h>

// ---------------------------------------------------------------------------
// GCN 2-layer forward:  out = log_softmax( A_hat * relu(A_hat * (x W1) + b1) W2 + b2 )
// A_hat = D^-1/2 (A + I) D^-1/2, deg on dst. Edge index arrives as int32.
//
// R11: pull kernels -> one-row-per-instruction gather. 64 lanes x half2 = one
// full 256B row per wave load (4 cachelines/instr vs 16 in r10), wave-uniform
// edge range (readfirstlane -> scalar col loads), pairwise fp16 tree add
// (v_pk_add_f16) then fp32 flush -> ~4x fewer inner VALU ops, no shfl tree.
// pull_agg2: 2 rows/instr via lane-half split + one shfl_xor(32).
// CSR build + MFMA GEMMs unchanged from r10.
// ---------------------------------------------------------------------------

#define BSHIFT 9
#define BSIZE  512            // nodes per bucket; NB = ceil(N/512) = 196 < 256
#define P2_T   1024
#define P2_I   16             // edges staged per thread in partition pass

using half8  = __attribute__((ext_vector_type(8))) _Float16;
using half2v = __attribute__((ext_vector_type(2))) _Float16;
using f32x4  = __attribute__((ext_vector_type(4))) float;

// --- pass 1: per-bucket edge counts (coalesced dst read, LDS histogram) ----
__global__ __launch_bounds__(256) void bucket_hist_kernel(const int* __restrict__ dst, int E,
                                                          unsigned int* __restrict__ bcount, int NB) {
    __shared__ unsigned int h[256];
    int t = threadIdx.x;
    h[t] = 0u;
    __syncthreads();
    for (int i = blockIdx.x * 256 + t; i < E; i += gridDim.x * 256)
        atomicAdd(&h[dst[i] >> BSHIFT], 1u);
    __syncthreads();
    if (t < NB && h[t]) atomicAdd(&bcount[t], h[t]);
}

// --- scan bucket counts -> bucket_base bb[0..NB], bucket_fill bf -----------
__global__ __launch_bounds__(256) void bucket_scan_kernel(const unsigned int* __restrict__ bcount,
                                                          unsigned int* __restrict__ bb,
                                                          unsigned int* __restrict__ bf,
                                                          int NB, int E) {
    __shared__ unsigned int s[256];
    int t = threadIdx.x;
    unsigned int v = (t < NB) ? bcount[t] : 0u;
    s[t] = v;
    __syncthreads();
    for (int off = 1; off < 256; off <<= 1) {
        unsigned int u = s[t];
        if (t >= off) u += s[t - off];
        __syncthreads();
        s[t] = u;
        __syncthreads();
    }
    if (t < NB) {
        unsigned int ex = s[t] - v;
        bb[t] = ex;
        bf[t] = ex;
    }
    if (t == 0) bb[NB] = (unsigned int)E;
}

// --- pass 2: partition edges into dst-buckets, packed src|dstLocal<<17 -----
__global__ __launch_bounds__(1024) void partition_kernel(const int* __restrict__ src,
                                                         const int* __restrict__ dst,
                                                         unsigned int* __restrict__ bucket_fill,
                                                         unsigned int* __restrict__ ebuf,
                                                         int E, int NB) {
    __shared__ unsigned int hist[256];
    __shared__ unsigned int cur[256];
    int t = threadIdx.x;
    if (t < 256) hist[t] = 0u;
    __syncthreads();
    size_t base = (size_t)blockIdx.x * (P2_T * P2_I);
    int sv[P2_I], dv[P2_I];
#pragma unroll
    for (int i = 0; i < P2_I; ++i) {
        size_t idx = base + (size_t)i * P2_T + t;
        if (idx < (size_t)E) {
            sv[i] = src[idx];
            dv[i] = dst[idx];
            atomicAdd(&hist[dv[i] >> BSHIFT], 1u);
        } else dv[i] = -1;
    }
    __syncthreads();
    if (t < NB && hist[t] > 0u) cur[t] = atomicAdd(&bucket_fill[t], hist[t]);
    __syncthreads();
#pragma unroll
    for (int i = 0; i < P2_I; ++i) {
        if (dv[i] >= 0) {
            int b = dv[i] >> BSHIFT;
            unsigned int pos = atomicAdd(&cur[b], 1u);
            ebuf[pos] = (unsigned int)sv[i] | ((unsigned int)(dv[i] & (BSIZE - 1)) << 17);
        }
    }
}

// --- pass 3: per-bucket deg/dinv/rowptr in LDS + scatter; cursor=rowend ----
__global__ __launch_bounds__(256) void bucket_scatter2_kernel(const unsigned int* __restrict__ ebuf,
                                                              const unsigned int* __restrict__ bb,
                                                              unsigned int* __restrict__ cursor,
                                                              unsigned int* __restrict__ deg,
                                                              float* __restrict__ dinv,
                                                              int* __restrict__ col, int N) {
    __shared__ unsigned int ldeg[BSIZE];
    __shared__ unsigned int lcur[BSIZE];
    __shared__ unsigned int part[256];
    int b = blockIdx.x, t = threadIdx.x;
    int node0 = b << BSHIFT;
    int nn = min(BSIZE, N - node0);
    ldeg[t] = 0u;
    ldeg[t + 256] = 0u;
    __syncthreads();
    unsigned int e0 = bb[b], e1 = bb[b + 1];
    for (unsigned int e = e0 + t; e < e1; e += 256)
        atomicAdd(&ldeg[ebuf[e] >> 17], 1u);
    __syncthreads();
    unsigned int a0 = ldeg[2 * t], a1 = ldeg[2 * t + 1];
    part[t] = a0 + a1;
    __syncthreads();
    for (int off = 1; off < 256; off <<= 1) {
        unsigned int u = part[t];
        if (t >= off) u += part[t - off];
        __syncthreads();
        part[t] = u;
        __syncthreads();
    }
    unsigned int ex = part[t] - (a0 + a1);
    lcur[2 * t]     = e0 + ex;
    lcur[2 * t + 1] = e0 + ex + a0;
    __syncthreads();
    for (unsigned int e = e0 + t; e < e1; e += 256) {
        unsigned int p = ebuf[e];
        unsigned int pos = atomicAdd(&lcur[p >> 17], 1u);
        col[pos] = (int)(p & 0x1FFFFu);
    }
    __syncthreads();
    for (int i = t; i < nn; i += 256) {
        unsigned int d = ldeg[i];
        deg[node0 + i] = d;
        dinv[node0 + i] = rsqrtf((float)(d + 1u));
        cursor[node0 + i] = lcur[i];
    }
}

// --- swizzle W1 (128x128) and W2 (128x64) into MFMA B-fragment order -------
// w1s[((c*4+s)*64+l)*8+j] = W[k][n], k=(l>>4)*8+j+32s, n=16c+(l&15)
__global__ __launch_bounds__(256) void swizzle_w_kernel(const float* __restrict__ W1,
                                                        const float* __restrict__ W2,
                                                        __half* __restrict__ w1s,
                                                        __half* __restrict__ w2s) {
    int t = threadIdx.x;
    for (int i = t; i < 8 * 4 * 64 * 8; i += 256) {   // W1: 8 col-tiles
        int j = i & 7, l = (i >> 3) & 63, s = (i >> 9) & 3, c = i >> 11;
        int k = ((l >> 4) * 8) + j + 32 * s;
        int nn = 16 * c + (l & 15);
        w1s[i] = __float2half(W1[k * 128 + nn]);
    }
    for (int i = t; i < 4 * 4 * 64 * 8; i += 256) {   // W2: 4 col-tiles
        int j = i & 7, l = (i >> 3) & 63, s = (i >> 9) & 3, c = i >> 11;
        int k = ((l >> 4) * 8) + j + 32 * s;
        int nn = 16 * c + (l & 15);
        w2s[i] = __float2half(W2[k * 64 + nn]);
    }
}

// --- GEMM1 (MFMA): Y[r,128] = f16( dinv[r] * (X[r,128] @ W1) ), X fp32 -----
__global__ __launch_bounds__(256) void gemm1_mfma_kernel(const float* __restrict__ X,
                                                         const __half* __restrict__ w1s,
                                                         const float* __restrict__ dinv,
                                                         __half* __restrict__ Y, int n) {
    int t = threadIdx.x;
    int wave = t >> 6, lane = t & 63;
    int quad = lane >> 4, m = lane & 15;
    int rowbase = blockIdx.x * 64 + wave * 16;
    int arow = rowbase + m;
    bool aok = arow < n;
    const float* xr = X + (size_t)arow * 128 + quad * 8;

    half8 afrag[4];
#pragma unroll
    for (int s = 0; s < 4; ++s) {
        float4 p0 = make_float4(0.f, 0.f, 0.f, 0.f), p1 = p0;
        if (aok) {
            p0 = *(const float4*)(xr + s * 32);
            p1 = *(const float4*)(xr + s * 32 + 4);
        }
        afrag[s][0] = (_Float16)p0.x; afrag[s][1] = (_Float16)p0.y;
        afrag[s][2] = (_Float16)p0.z; afrag[s][3] = (_Float16)p0.w;
        afrag[s][4] = (_Float16)p1.x; afrag[s][5] = (_Float16)p1.y;
        afrag[s][6] = (_Float16)p1.z; afrag[s][7] = (_Float16)p1.w;
    }

    const half8* bp = (const half8*)w1s;
    f32x4 acc[8];
#pragma unroll
    for (int c = 0; c < 8; ++c) acc[c] = (f32x4){0.f, 0.f, 0.f, 0.f};
#pragma unroll
    for (int c = 0; c < 8; ++c)
#pragma unroll
        for (int s = 0; s < 4; ++s)
            acc[c] = __builtin_amdgcn_mfma_f32_16x16x32_f16(afrag[s], bp[(c * 4 + s) * 64 + lane], acc[c], 0, 0, 0);

#pragma unroll
    for (int i = 0; i < 4; ++i) {
        int row = rowbase + quad * 4 + i;
        if (row < n) {
            float w = dinv[row];
            __half* yr = Y + (size_t)row * 128 + m;
#pragma unroll
            for (int c = 0; c < 8; ++c) yr[c * 16] = __float2half(acc[c][i] * w);
        }
    }
}

// --- GEMM2 (MFMA): Y[r,64] = f16( dinv[r] * (Xh[r,128] @ W2) ), X fp16 -----
__global__ __launch_bounds__(256) void gemm2_mfma_kernel(const __half* __restrict__ X,
                                                         const __half* __restrict__ w2s,
                                                         const float* __restrict__ dinv,
                                                         __half* __restrict__ Y, int n) {
    int t = threadIdx.x;
    int wave = t >> 6, lane = t & 63;
    int quad = lane >> 4, m = lane & 15;
    int rowbase = blockIdx.x * 64 + wave * 16;
    int arow = rowbase + m;
    bool aok = arow < n;
    const __half* xr = X + (size_t)arow * 128 + quad * 8;

    half8 afrag[4];
#pragma unroll
    for (int s = 0; s < 4; ++s) {
        if (aok) afrag[s] = *(const half8*)(xr + s * 32);
        else     afrag[s] = (half8){0, 0, 0, 0, 0, 0, 0, 0};
    }

    const half8* bp = (const half8*)w2s;
    f32x4 acc[4];
#pragma unroll
    for (int c = 0; c < 4; ++c) acc[c] = (f32x4){0.f, 0.f, 0.f, 0.f};
#pragma unroll
    for (int c = 0; c < 4; ++c)
#pragma unroll
        for (int s = 0; s < 4; ++s)
            acc[c] = __builtin_amdgcn_mfma_f32_16x16x32_f16(afrag[s], bp[(c * 4 + s) * 64 + lane], acc[c], 0, 0, 0);

#pragma unroll
    for (int i = 0; i < 4; ++i) {
        int row = rowbase + quad * 4 + i;
        if (row < n) {
            float w = dinv[row];
            __half* yr = Y + (size_t)row * 64 + m;
#pragma unroll
            for (int c = 0; c < 4; ++c) yr[c * 16] = __float2half(acc[c][i] * w);
        }
    }
}

// --- pull layer 1: H[d] = relu(dinv[d]*(T'[d] + sum T'[col]) + b1), F=128 --
// R11: 1 node/wave; one full 256B row per wave load (64 lanes x half2).
// Wave-uniform edge range -> scalar col loads; pk_add_f16 tree + fp32 flush.
__global__ __launch_bounds__(256) void pull_agg1_kernel(const __half* __restrict__ T,
                                                        const int* __restrict__ col,
                                                        const unsigned int* __restrict__ cursor,
                                                        const unsigned int* __restrict__ deg,
                                                        const float* __restrict__ dinv,
                                                        const float* __restrict__ b1,
                                                        __half* __restrict__ H, int N) {
    int node = blockIdx.x * 4 + (threadIdx.x >> 6);
    if (node >= N) return;
    int lane = threadIdx.x & 63;
    unsigned int end = cursor[node];
    unsigned int e = end - deg[node];
    end = __builtin_amdgcn_readfirstlane(end);
    e   = __builtin_amdgcn_readfirstlane(e);
    const half2v* __restrict__ Tv = (const half2v*)T;   // row = 64 half2

    half2v self = Tv[(unsigned int)node * 64u + lane];
    float acc0 = (float)self[0], acc1 = (float)self[1];

    for (; e + 8 <= end; e += 8) {                      // 8 rows in flight
        unsigned int s0 = (unsigned int)col[e];
        unsigned int s1 = (unsigned int)col[e + 1];
        unsigned int s2 = (unsigned int)col[e + 2];
        unsigned int s3 = (unsigned int)col[e + 3];
        unsigned int s4 = (unsigned int)col[e + 4];
        unsigned int s5 = (unsigned int)col[e + 5];
        unsigned int s6 = (unsigned int)col[e + 6];
        unsigned int s7 = (unsigned int)col[e + 7];
        half2v v0 = Tv[s0 * 64u + lane];
        half2v v1 = Tv[s1 * 64u + lane];
        half2v v2 = Tv[s2 * 64u + lane];
        half2v v3 = Tv[s3 * 64u + lane];
        half2v v4 = Tv[s4 * 64u + lane];
        half2v v5 = Tv[s5 * 64u + lane];
        half2v v6 = Tv[s6 * 64u + lane];
        half2v v7 = Tv[s7 * 64u + lane];
        half2v t0 = (v0 + v1) + (v2 + v3);              // fp16 tree, 2 roundings
        half2v t1 = (v4 + v5) + (v6 + v7);
        acc0 += (float)t0[0] + (float)t1[0];
        acc1 += (float)t0[1] + (float)t1[1];
    }
    for (; e + 4 <= end; e += 4) {
        unsigned int s0 = (unsigned int)col[e];
        unsigned int s1 = (unsigned int)col[e + 1];
        unsigned int s2 = (unsigned int)col[e + 2];
        unsigned int s3 = (unsigned int)col[e + 3];
        half2v v0 = Tv[s0 * 64u + lane];
        half2v v1 = Tv[s1 * 64u + lane];
        half2v v2 = Tv[s2 * 64u + lane];
        half2v v3 = Tv[s3 * 64u + lane];
        half2v t = (v0 + v1) + (v2 + v3);
        acc0 += (float)t[0];
        acc1 += (float)t[1];
    }
    for (; e < end; ++e) {                              // <=3 singles, fp32 path
        half2v v0 = Tv[(unsigned int)col[e] * 64u + lane];
        acc0 += (float)v0[0];
        acc1 += (float)v0[1];
    }

    float w = dinv[node];
    float2 b = ((const float2*)b1)[lane];
    float hx = fmaxf(fmaf(w, acc0, b.x), 0.f);
    float hy = fmaxf(fmaf(w, acc1, b.y), 0.f);
    ((__half2*)H)[(unsigned int)node * 64u + lane] = __floats2half2_rn(hx, hy);
}

// --- pull layer 2 + logsoftmax: out[d] = lsm(dinv[d]*sum + b2), F=64 -------
// R11: 1 node/wave; 2 rows per wave load (lane-half split, 32 x half2 each);
// one shfl_xor(32) combine, LSM over 32 lanes.
__global__ __launch_bounds__(256) void pull_agg2_kernel(const __half* __restrict__ T,
                                                        const int* __restrict__ col,
                                                        const unsigned int* __restrict__ cursor,
                                                        const unsigned int* __restrict__ deg,
                                                        const float* __restrict__ dinv,
                                                        const float* __restrict__ b2,
                                                        float* __restrict__ OUT, int N) {
    int node = blockIdx.x * 4 + (threadIdx.x >> 6);
    if (node >= N) return;
    int lane = threadIdx.x & 63;
    int h = lane >> 5, c2 = lane & 31;                  // edge-half / col pair
    unsigned int end = cursor[node];
    unsigned int e = end - deg[node];
    end = __builtin_amdgcn_readfirstlane(end);
    e   = __builtin_amdgcn_readfirstlane(e);
    const half2v* __restrict__ Tv = (const half2v*)T;   // row = 32 half2

    float acc0 = 0.f, acc1 = 0.f;
    if (h == 0) {                                       // self loop on half 0
        half2v s = Tv[(unsigned int)node * 32u + c2];
        acc0 = (float)s[0];
        acc1 = (float)s[1];
    }

    for (; e + 16 <= end; e += 16) {                    // 8 rows/half in flight
        unsigned int s0 = (unsigned int)col[e + h];
        unsigned int s1 = (unsigned int)col[e + 2 + h];
        unsigned int s2 = (unsigned int)col[e + 4 + h];
        unsigned int s3 = (unsigned int)col[e + 6 + h];
        unsigned int s4 = (unsigned int)col[e + 8 + h];
        unsigned int s5 = (unsigned int)col[e + 10 + h];
        unsigned int s6 = (unsigned int)col[e + 12 + h];
        unsigned int s7 = (unsigned int)col[e + 14 + h];
        half2v v0 = Tv[s0 * 32u + c2];
        half2v v1 = Tv[s1 * 32u + c2];
        half2v v2 = Tv[s2 * 32u + c2];
        half2v v3 = Tv[s3 * 32u + c2];
        half2v v4 = Tv[s4 * 32u + c2];
        half2v v5 = Tv[s5 * 32u + c2];
        half2v v6 = Tv[s6 * 32u + c2];
        half2v v7 = Tv[s7 * 32u + c2];
        half2v t0 = (v0 + v1) + (v2 + v3);
        half2v t1 = (v4 + v5) + (v6 + v7);
        acc0 += (float)t0[0] + (float)t1[0];
        acc1 += (float)t0[1] + (float)t1[1];
    }
    for (; e + 4 <= end; e += 4) {                      // 2 rows/half
        unsigned int s0 = (unsigned int)col[e + h];
        unsigned int s1 = (unsigned int)col[e + 2 + h];
        half2v v0 = Tv[s0 * 32u + c2];
        half2v v1 = Tv[s1 * 32u + c2];
        half2v t = v0 + v1;
        acc0 += (float)t[0];
        acc1 += (float)t[1];
    }
    if (e + 2 <= end) {                                 // 1 row/half
        half2v v0 = Tv[(unsigned int)col[e + h] * 32u + c2];
        acc0 += (float)v0[0];
        acc1 += (float)v0[1];
        e += 2;
    }
    if (e < end && h == 0) {                            // final odd edge
        half2v v0 = Tv[(unsigned int)col[e] * 32u + c2];
        acc0 += (float)v0[0];
        acc1 += (float)v0[1];
    }

    acc0 += __shfl_xor(acc0, 32);                       // combine halves
    acc1 += __shfl_xor(acc1, 32);

    float w = dinv[node];
    float2 b = ((const float2*)b2)[c2];
    float vx = fmaf(w, acc0, b.x);
    float vy = fmaf(w, acc1, b.y);
    float m = fmaxf(vx, vy);
#pragma unroll
    for (int off = 16; off > 0; off >>= 1) m = fmaxf(m, __shfl_xor(m, off));
    float sum = __expf(vx - m) + __expf(vy - m);
#pragma unroll
    for (int off = 16; off > 0; off >>= 1) sum += __shfl_xor(sum, off);
    float ls = m + logf(sum);
    if (h == 0) {
        float2 o;
        o.x = vx - ls;
        o.y = vy - ls;
        ((float2*)OUT)[(unsigned int)node * 32u + c2] = o;
    }
}

extern "C" void kernel_launch(void* const* d_in, const int* in_sizes, int n_in,
                              void* d_out, int out_size, void* d_ws, size_t ws_size,
                              hipStream_t stream) {
    const float* x   = (const float*)d_in[0];
    const int*   ei  = (const int*)d_in[1];   // int32 per harness contract
    const float* W1  = (const float*)d_in[2];
    const float* b1  = (const float*)d_in[3];
    const float* W2  = (const float*)d_in[4];
    const float* b2  = (const float*)d_in[5];
    float*       out = (float*)d_out;

    const int N = in_sizes[0] / 128;      // 100000
    const int E = in_sizes[1] / 2;        // 1600000
    const int* src = ei;
    const int* dst = ei + E;
    const int NB = (N + BSIZE - 1) >> BSHIFT;   // dst buckets (196 <= 256)

    // workspace layout
    char* ws = (char*)d_ws;
    size_t off = 0;
    auto alloc = [&](size_t bytes) { void* p = ws + off; off = (off + bytes + 255) & ~(size_t)255; return p; };
    unsigned int* deg    = (unsigned int*)alloc((size_t)N * 4);
    float*        dinv   = (float*)alloc((size_t)N * 4);
    unsigned int* cursor = (unsigned int*)alloc((size_t)N * 4);
    unsigned int* bcount = (unsigned int*)alloc(256 * 4);
    unsigned int* bb     = (unsigned int*)alloc(257 * 4);       // bucket_base
    unsigned int* bf     = (unsigned int*)alloc(256 * 4);       // bucket_fill
    __half*       w1s    = (__half*)alloc(128 * 128 * 2);       // swizzled W1
    __half*       w2s    = (__half*)alloc(128 * 64 * 2);        // swizzled W2
    int*          col    = (int*)alloc((size_t)E * 4);
    __half*       A      = (__half*)alloc((size_t)N * 128 * 2); // T1'/T2' fp16
    __half*       B      = (__half*)alloc((size_t)N * 128 * 2); // h fp16
    unsigned int* ebuf   = (unsigned int*)alloc((size_t)E * 4);

    // 1. CSR build: bucket hist -> scan -> partition -> per-bucket scatter
    hipMemsetAsync(bcount, 0, 256 * 4, stream);
    bucket_hist_kernel<<<(E + 4095) / 4096, 256, 0, stream>>>(dst, E, bcount, NB);
    bucket_scan_kernel<<<1, 256, 0, stream>>>(bcount, bb, bf, NB, E);
    partition_kernel<<<(E + P2_T * P2_I - 1) / (P2_T * P2_I), P2_T, 0, stream>>>(src, dst, bf, ebuf, E, NB);
    bucket_scatter2_kernel<<<NB, 256, 0, stream>>>(ebuf, bb, cursor, deg, dinv, col, N);
    // now cursor[i] == rowend(i); rowstart(i) = cursor[i] - deg[i]; dinv ready

    // 1b. swizzle weights into MFMA fragment order (runs alongside CSR chain)
    swizzle_w_kernel<<<1, 256, 0, stream>>>(W1, W2, w1s, w2s);

    // 2. T1' = dinv * (x @ W1) [MFMA, fp16 out];  h = relu(dinv*(pull) + b1)
    gemm1_mfma_kernel<<<(N + 63) / 64, 256, 0, stream>>>(x, w1s, dinv, A, N);
    pull_agg1_kernel<<<(N + 3) / 4, 256, 0, stream>>>(A, col, cursor, deg, dinv, b1, B, N);

    // 3. T2' = dinv * (h @ W2) [MFMA];  out = logsoftmax(dinv*(pull) + b2)
    gemm2_mfma_kernel<<<(N + 63) / 64, 256, 0, stream>>>(B, w2s, dinv, A, N);
    pull_agg2_kernel<<<(N + 3) / 4, 256, 0, stream>>>(A, col, cursor, deg, dinv, b2, out, N);
}